// Round 4
// baseline (222.619 us; speedup 1.0000x reference)
//
#include <hip/hip_runtime.h>
#include <hip/hip_bf16.h>
#include <string.h>

#define Bsz 2
#define Tsz 2048
#define Dsz 1024
#define NHsz 16
#define Msz (Bsz*Tsz)  // 4096 rows total

typedef unsigned short bfu;  // bf16 bit pattern
typedef __attribute__((ext_vector_type(8))) short short8;   // MFMA A/B frag: 8 bf16
typedef __attribute__((ext_vector_type(4))) short short4v;
typedef __attribute__((ext_vector_type(4))) float floatx4;  // MFMA C/D frag

__device__ __forceinline__ bfu f2bf(float f) {
  unsigned int u = __builtin_bit_cast(unsigned int, f);
  u += 0x7fffu + ((u >> 16) & 1u);
  return (bfu)(u >> 16);
}

__device__ __forceinline__ short4v pack4bf(float a, float b, float c_, float d) {
  // v_cvt_pk_bf16_f32: 2 ops for 4 values (memcpy = register move; bf162 not bit_cast-able)
  __hip_bfloat162 h01 = __float22bfloat162_rn(make_float2(a, b));
  __hip_bfloat162 h23 = __float22bfloat162_rn(make_float2(c_, d));
  uint2 uu;
  memcpy(&uu.x, &h01, 4);
  memcpy(&uu.y, &h23, 4);
  return __builtin_bit_cast(short4v, uu);
}

__device__ __forceinline__ void async16(const void* g, void* l) {
  void* gnc = (void*)g;
  __builtin_amdgcn_global_load_lds((__attribute__((address_space(1))) void*)gnc,
                                   (__attribute__((address_space(3))) void*)l,
                                   16, 0, 0);
}

// ---------------- x: fp32 -> bf16 ----------------
__global__ __launch_bounds__(256) void convert_x(const float* __restrict__ x,
                                                 bfu* __restrict__ xb) {
  int i = blockIdx.x * 256 + threadIdx.x;
  float4 v = ((const float4*)x)[i];
  short4v o;
  o[0] = (short)f2bf(v.x); o[1] = (short)f2bf(v.y);
  o[2] = (short)f2bf(v.z); o[3] = (short)f2bf(v.w);
  *(short4v*)(xb + (size_t)i * 4) = o;
}

// ---------------- W (KxN fp32) -> WT (NxK bf16), z = 4 weights ----------------
__global__ __launch_bounds__(256) void transpose_w(const float* __restrict__ W0, const float* __restrict__ W1,
                                                   const float* __restrict__ W2, const float* __restrict__ W3,
                                                   bfu* __restrict__ wt) {
  __shared__ float tile[32][33];
  const float* W = blockIdx.z == 0 ? W0 : blockIdx.z == 1 ? W1 : blockIdx.z == 2 ? W2 : W3;
  bfu* WT = wt + (size_t)blockIdx.z * Dsz * Dsz;
  int tx = threadIdx.x, ty = threadIdx.y;           // 32 x 8
  int kb = blockIdx.y * 32, nb = blockIdx.x * 32;
#pragma unroll
  for (int i = 0; i < 4; ++i)
    tile[ty + i*8][tx] = W[(size_t)(kb + ty + i*8) * Dsz + nb + tx];
  __syncthreads();
#pragma unroll
  for (int i = 0; i < 4; ++i)
    WT[(size_t)(nb + ty + i*8) * Dsz + kb + tx] = f2bf(tile[tx][ty + i*8]);
}

// ---------------- 128x128 bf16 MFMA GEMM: C = A(MxK) * BT(NxK)^T ----------------
template <bool F32OUT>
__global__ __launch_bounds__(256) void gemm128(const bfu* __restrict__ A, const bfu* __restrict__ Bt0,
                                               void* __restrict__ C0, int K, int N,
                                               size_t strideB, size_t strideC, float scale0) {
  const int tid = threadIdx.x, wave = tid >> 6, lane = tid & 63;
  const int g = lane >> 4, c = lane & 15;
  const int m0 = blockIdx.y * 128, n0 = blockIdx.x * 128;
  const bfu* Bt = Bt0 + strideB * blockIdx.z;
  const float scale = (blockIdx.z == 0) ? scale0 : 1.0f;
  __shared__ bfu As[128 * 32];
  __shared__ bfu Bs[128 * 32];
  floatx4 acc[4][4] = {};
  const int srow = lane >> 2, scol = (lane & 3) * 8;
  const bfu* gA = A  + (size_t)(m0 + srow) * K + scol;
  const bfu* gB = Bt + (size_t)(n0 + srow) * K + scol;
  const int wm = (wave >> 1) * 64, wn = (wave & 1) * 64;
  for (int k0 = 0; k0 < K; k0 += 32) {
    __syncthreads();
#pragma unroll
    for (int cc = 0; cc < 2; ++cc) {
      const int chunk = wave * 2 + cc;
      async16(gA + (size_t)chunk * 16 * K + k0, &As[chunk * 512]);
      async16(gB + (size_t)chunk * 16 * K + k0, &Bs[chunk * 512]);
    }
    __syncthreads();
    short8 afr[4], bfr[4];
#pragma unroll
    for (int t = 0; t < 4; ++t) afr[t] = *(const short8*)&As[(wm + t*16 + c) * 32 + g * 8];
#pragma unroll
    for (int t = 0; t < 4; ++t) bfr[t] = *(const short8*)&Bs[(wn + t*16 + c) * 32 + g * 8];
#pragma unroll
    for (int i = 0; i < 4; ++i)
#pragma unroll
      for (int j = 0; j < 4; ++j)
        acc[i][j] = __builtin_amdgcn_mfma_f32_16x16x32_bf16(afr[i], bfr[j], acc[i][j], 0, 0, 0);
  }
  const bool vtrans = (!F32OUT) && (blockIdx.z == 2);
#pragma unroll
  for (int i = 0; i < 4; ++i) {
#pragma unroll
    for (int j = 0; j < 4; ++j) {
      const int m = m0 + wm + i*16 + g*4;
      const int n = n0 + wn + j*16 + c;
      if (vtrans) {
        bfu* vtp = (bfu*)C0 + (size_t)2 * strideC;
        size_t o = ((size_t)((m >> 11) * 16 + (n >> 6)) * 64 + (n & 63)) * Tsz + (m & 2047);
        short4v pk;
#pragma unroll
        for (int r = 0; r < 4; ++r) pk[r] = (short)f2bf(acc[i][j][r]);
        *(short4v*)&vtp[o] = pk;
      } else {
#pragma unroll
        for (int r = 0; r < 4; ++r) {
          float v = acc[i][j][r] * scale;
          if (F32OUT) ((float*)C0)[(size_t)(m + r) * N + n] = v;
          else        ((bfu*)C0)[strideC * blockIdx.z + (size_t)(m + r) * N + n] = f2bf(v);
        }
      }
    }
  }
}

// ---------------- causal flash attention (S^T formulation, 128q x 128k tiles) ----------------
// Q,K natural [b*T+t][h*64+d]; V transposed as VT[b][h][d][t]. Q pre-scaled by log2e/8.
// Grid 512 blocks: lin<256 -> j=15-p, else j=p (p=(lin>>5)&7, bh=lin&31). Blocks lin and
// lin+256 co-reside per XCD round-robin -> every CU gets exactly 17 key-iters.
// Block: 4 waves x 32 q-rows (2 x 16-row frags). Dbuf K/V via global_load_lds; prefetch
// issued before compute, single barrier per iter. K-frags held in VGPRs across q-frags.
__global__ __launch_bounds__(256, 2) void attn_kernel(const bfu* __restrict__ qkv,
                                                      bfu* __restrict__ obuf) {
  const int tid = threadIdx.x, wave = tid >> 6, lane = tid & 63;
  const int g = (lane >> 4) & 3, c = lane & 15, c7 = c & 7;
  const int lin = blockIdx.x;
  const int bh = lin & 31, p = (lin >> 5) & 7;
  const int j = (lin < 256) ? (15 - p) : p;
  const int b = bh >> 4, h = bh & 15;
  const size_t hb = (size_t)b * Tsz * Dsz + h * 64;
  const bfu* Qp = qkv + hb;
  const bfu* Kp = qkv + (size_t)Msz * Dsz + hb;
  const bfu* Vt = qkv + (size_t)2 * Msz * Dsz + (size_t)bh * 64 * Tsz;

  __shared__ bfu Ks[2][128 * 64];   // [key][d], d-granule ^= key&7
  __shared__ bfu Vs[2][64 * 128];   // [d][key], key-granule ^= d&7
  __shared__ bfu Ps[4][16 * 128];   // per-wave P, reused across q-frags

  const int kst_row = lane >> 3;
  const int kst_off = ((lane & 7) ^ kst_row) << 3;
  const int vst_row = lane >> 4;

  const int qw = j * 128 + wave * 32;

  short8 bq[2][2];                  // Q B-frags [qf][kk]
#pragma unroll
  for (int qf = 0; qf < 2; ++qf)
#pragma unroll
    for (int kk = 0; kk < 2; ++kk)
      bq[qf][kk] = *(const short8*)(Qp + (size_t)(qw + qf*16 + c) * Dsz + kk*32 + g*8);

  floatx4 acc[2][4] = {};
  float mi[2] = {-3.0e38f, -3.0e38f}, li[2] = {0.0f, 0.0f};

  // stage kt=0 -> buf0
#pragma unroll
  for (int cc = 0; cc < 4; ++cc) {
    const int ch = wave * 4 + cc;
    async16(Kp + (size_t)(ch*8 + kst_row) * Dsz + kst_off, &Ks[0][ch * 512]);
    const int drow = ch * 4 + vst_row;
    async16(Vt + (size_t)drow * Tsz + (((lane & 15) ^ (drow & 7)) << 3), &Vs[0][ch * 512]);
  }
  __syncthreads();

  for (int kt = 0; kt <= j; ++kt) {
    const int cur = kt & 1;
    if (kt < j) {   // prefetch next tile into other buffer (overlaps with compute below)
#pragma unroll
      for (int cc = 0; cc < 4; ++cc) {
        const int ch = wave * 4 + cc;
        async16(Kp + (size_t)((kt+1)*128 + ch*8 + kst_row) * Dsz + kst_off, &Ks[cur ^ 1][ch * 512]);
        const int drow = ch * 4 + vst_row;
        async16(Vt + (size_t)drow * Tsz + (kt+1)*128 + (((lane & 15) ^ (drow & 7)) << 3),
                &Vs[cur ^ 1][ch * 512]);
      }
    }

    // K fragments into registers (shared across both q-frags)
    short8 kfr[2][8];
#pragma unroll
    for (int kk = 0; kk < 2; ++kk)
#pragma unroll
      for (int mk = 0; mk < 8; ++mk)
        kfr[kk][mk] = *(const short8*)&Ks[cur][(mk*16 + c) * 64 + (((kk*4 + g) ^ c7) << 3)];

    const bool diag = (kt == j);
#pragma unroll
    for (int qf = 0; qf < 2; ++qf) {
      const int wp = wave * 2 + qf;                    // this q-frag's diagonal group
      const int mk_hi = diag ? (wp + 1) : 8;
      const int kc_hi = diag ? ((wp >> 1) + 1) : 4;

      floatx4 st[8];
#pragma unroll
      for (int mk = 0; mk < 8; ++mk) {
        if (mk < mk_hi) {
          floatx4 z = {};
          z = __builtin_amdgcn_mfma_f32_16x16x32_bf16(kfr[0][mk], bq[qf][0], z, 0, 0, 0);
          st[mk] = __builtin_amdgcn_mfma_f32_16x16x32_bf16(kfr[1][mk], bq[qf][1], z, 0, 0, 0);
        }
      }
      if (diag) {   // partial mask on the diagonal 16x16 group
#pragma unroll
        for (int mk = 0; mk < 8; ++mk)
          if (mk == wp) {
#pragma unroll
            for (int r = 0; r < 4; ++r)
              if (g*4 + r > c) st[mk][r] = -1.0e38f;
          }
      }

      float mloc = -3.0e38f;
#pragma unroll
      for (int mk = 0; mk < 8; ++mk)
        if (mk < mk_hi) {
#pragma unroll
          for (int r = 0; r < 4; ++r) mloc = fmaxf(mloc, st[mk][r]);
        }
      mloc = fmaxf(mloc, __shfl_xor(mloc, 16));
      mloc = fmaxf(mloc, __shfl_xor(mloc, 32));
      const float mnew = fmaxf(mi[qf], mloc);
      const float alpha = exp2f(mi[qf] - mnew);
      mi[qf] = mnew;

      float sum = 0.0f;
#pragma unroll
      for (int mk = 0; mk < 8; ++mk)
        if (mk < mk_hi) {
          float pr[4];
#pragma unroll
          for (int r = 0; r < 4; ++r) { pr[r] = exp2f(st[mk][r] - mnew); sum += pr[r]; }
          *(short4v*)&Ps[wave][c * 128 + (((mk*2 + (g >> 1)) ^ c7) << 3) + ((g & 1) << 2)] =
              pack4bf(pr[0], pr[1], pr[2], pr[3]);
        }
      if (diag && !(wp & 1)) {   // zero-fill group wp+1 (read by PV but never computed)
        short4v z4 = {};
        *(short4v*)&Ps[wave][c * 128 + ((((wp+1)*2 + (g >> 1)) ^ c7) << 3) + ((g & 1) << 2)] = z4;
      }
      sum += __shfl_xor(sum, 16);
      sum += __shfl_xor(sum, 32);
      li[qf] = li[qf] * alpha + sum;

      float al[4];
#pragma unroll
      for (int r = 0; r < 4; ++r) al[r] = __shfl(alpha, (lane & 48) | (g*4 + r));
#pragma unroll
      for (int nd = 0; nd < 4; ++nd)
#pragma unroll
        for (int r = 0; r < 4; ++r) acc[qf][nd][r] *= al[r];

      // O += P * V
#pragma unroll
      for (int kc = 0; kc < 4; ++kc)
        if (kc < kc_hi) {
          const int sl = ((kc*4 + g) ^ c7) << 3;
          const short8 pf = *(const short8*)&Ps[wave][c * 128 + sl];
#pragma unroll
          for (int nd = 0; nd < 4; ++nd) {
            const short8 vf = *(const short8*)&Vs[cur][(nd*16 + c) * 128 + sl];
            acc[qf][nd] = __builtin_amdgcn_mfma_f32_16x16x32_bf16(pf, vf, acc[qf][nd], 0, 0, 0);
          }
        }
    }
    __syncthreads();   // readers of buf[cur] done; drains prefetch DMA into buf[cur^1]
  }

  // epilogue
#pragma unroll
  for (int qf = 0; qf < 2; ++qf) {
    float inv[4];
#pragma unroll
    for (int r = 0; r < 4; ++r) inv[r] = 1.0f / __shfl(li[qf], (lane & 48) | (g*4 + r));
#pragma unroll
    for (int nd = 0; nd < 4; ++nd)
#pragma unroll
      for (int r = 0; r < 4; ++r)
        obuf[(size_t)(b * Tsz + qw + qf*16 + g*4 + r) * Dsz + h * 64 + nd*16 + c] =
            f2bf(acc[qf][nd][r] * inv[r]);
  }
}

extern "C" void kernel_launch(void* const* d_in, const int* in_sizes, int n_in,
                              void* d_out, int out_size, void* d_ws, size_t ws_size,
                              hipStream_t stream) {
  const float* x  = (const float*)d_in[0];
  const float* Wq = (const float*)d_in[1];
  const float* Wk = (const float*)d_in[2];
  const float* Wv = (const float*)d_in[3];
  const float* Wo = (const float*)d_in[4];
  float* out = (float*)d_out;

  bfu* xb   = (bfu*)d_ws;
  bfu* wt   = xb  + (size_t)Msz * Dsz;
  bfu* qkv  = wt  + (size_t)4 * Dsz * Dsz;
  bfu* obuf = qkv + (size_t)3 * Msz * Dsz;

  convert_x<<<dim3(Msz * Dsz / (256 * 4)), dim3(256), 0, stream>>>(x, xb);
  transpose_w<<<dim3(32, 32, 4), dim3(32, 8), 0, stream>>>(Wq, Wk, Wv, Wo, wt);
  gemm128<false><<<dim3(Dsz / 128, Msz / 128, 3), dim3(256), 0, stream>>>(
      xb, wt, (void*)qkv, Dsz, Dsz, (size_t)Dsz * Dsz, (size_t)Msz * Dsz,
      0.125f * 1.44269504088896f);
  attn_kernel<<<dim3(512), dim3(256), 0, stream>>>(qkv, obuf);
  gemm128<true><<<dim3(Dsz / 128, Msz / 128, 1), dim3(256), 0, stream>>>(
      obuf, wt + (size_t)3 * Dsz * Dsz, (void*)out, Dsz, Dsz, (size_t)0, (size_t)0, 1.0f);
}

// Round 5
// 210.882 us; speedup vs baseline: 1.0557x; 1.0557x over previous
//
#include <hip/hip_runtime.h>
#include <hip/hip_bf16.h>
#include <string.h>

#define Bsz 2
#define Tsz 2048
#define Dsz 1024
#define NHsz 16
#define Msz (Bsz*Tsz)  // 4096 rows total

typedef unsigned short bfu;  // bf16 bit pattern
typedef __attribute__((ext_vector_type(8))) short short8;   // MFMA A/B frag: 8 bf16
typedef __attribute__((ext_vector_type(4))) short short4v;
typedef __attribute__((ext_vector_type(4))) float floatx4;  // MFMA C/D frag

__device__ __forceinline__ bfu f2bf(float f) {
  unsigned int u = __builtin_bit_cast(unsigned int, f);
  u += 0x7fffu + ((u >> 16) & 1u);
  return (bfu)(u >> 16);
}

__device__ __forceinline__ short4v pack4bf(float a, float b, float c_, float d) {
  // v_cvt_pk_bf16_f32: 2 ops for 4 values
  __hip_bfloat162 h01 = __float22bfloat162_rn(make_float2(a, b));
  __hip_bfloat162 h23 = __float22bfloat162_rn(make_float2(c_, d));
  uint2 uu;
  memcpy(&uu.x, &h01, 4);
  memcpy(&uu.y, &h23, 4);
  return __builtin_bit_cast(short4v, uu);
}

__device__ __forceinline__ short8 pack8bf(float4 a, float4 b) {
  __hip_bfloat162 h0 = __float22bfloat162_rn(make_float2(a.x, a.y));
  __hip_bfloat162 h1 = __float22bfloat162_rn(make_float2(a.z, a.w));
  __hip_bfloat162 h2 = __float22bfloat162_rn(make_float2(b.x, b.y));
  __hip_bfloat162 h3 = __float22bfloat162_rn(make_float2(b.z, b.w));
  uint4 u;
  memcpy(&u.x, &h0, 4); memcpy(&u.y, &h1, 4);
  memcpy(&u.z, &h2, 4); memcpy(&u.w, &h3, 4);
  return __builtin_bit_cast(short8, u);
}

__device__ __forceinline__ void async16(const void* g, void* l) {
  void* gnc = (void*)g;
  __builtin_amdgcn_global_load_lds((__attribute__((address_space(1))) void*)gnc,
                                   (__attribute__((address_space(3))) void*)l,
                                   16, 0, 0);
}

// ---------------- W (KxN fp32) -> WT (NxK bf16), z = 4 weights ----------------
__global__ __launch_bounds__(256) void transpose_w(const float* __restrict__ W0, const float* __restrict__ W1,
                                                   const float* __restrict__ W2, const float* __restrict__ W3,
                                                   bfu* __restrict__ wt) {
  __shared__ float tile[32][33];
  const float* W = blockIdx.z == 0 ? W0 : blockIdx.z == 1 ? W1 : blockIdx.z == 2 ? W2 : W3;
  bfu* WT = wt + (size_t)blockIdx.z * Dsz * Dsz;
  int tx = threadIdx.x, ty = threadIdx.y;           // 32 x 8
  int kb = blockIdx.y * 32, nb = blockIdx.x * 32;
#pragma unroll
  for (int i = 0; i < 4; ++i)
    tile[ty + i*8][tx] = W[(size_t)(kb + ty + i*8) * Dsz + nb + tx];
  __syncthreads();
#pragma unroll
  for (int i = 0; i < 4; ++i)
    WT[(size_t)(nb + ty + i*8) * Dsz + kb + tx] = f2bf(tile[tx][ty + i*8]);
}

// ---------------- 128x128 bf16 MFMA GEMM: C = A(MxK) * BT(NxK)^T ----------------
// AF32: A is fp32, staged through VGPRs with fused bf16 conversion (software-pipelined).
// z==0 gets scale0 (Q path). z==2 writes V transposed: VT[b][h][d][t].
template <bool F32OUT, bool AF32>
__global__ __launch_bounds__(256) void gemm128(const void* __restrict__ Ain, const bfu* __restrict__ Bt0,
                                               void* __restrict__ C0, int K, int N,
                                               size_t strideB, size_t strideC, float scale0) {
  const int tid = threadIdx.x, wave = tid >> 6, lane = tid & 63;
  const int g = lane >> 4, c = lane & 15;
  const int m0 = blockIdx.y * 128, n0 = blockIdx.x * 128;
  const bfu* Bt = Bt0 + strideB * blockIdx.z;
  const float scale = (blockIdx.z == 0) ? scale0 : 1.0f;
  __shared__ bfu As[128 * 32];
  __shared__ bfu Bs[128 * 32];
  floatx4 acc[4][4] = {};
  const int srow = lane >> 2, scol = (lane & 3) * 8;
  const bfu* gB = Bt + (size_t)(n0 + srow) * K + scol;
  const int wm = (wave >> 1) * 64, wn = (wave & 1) * 64;

  short8 areg[2];
  if (AF32) {   // preload k0=0 A-chunks as fp32, convert in regs
#pragma unroll
    for (int cc = 0; cc < 2; ++cc) {
      const float* pa = (const float*)Ain +
          (size_t)(m0 + (wave*2 + cc)*16 + srow) * K + scol;
      areg[cc] = pack8bf(((const float4*)pa)[0], ((const float4*)pa)[1]);
    }
  }
  const bfu* gA = AF32 ? nullptr : (const bfu*)Ain + (size_t)(m0 + srow) * K + scol;

  for (int k0 = 0; k0 < K; k0 += 32) {
    __syncthreads();               // prior reads done before overwrite
#pragma unroll
    for (int cc = 0; cc < 2; ++cc) {
      const int chunk = wave * 2 + cc;
      if (AF32) *(short8*)&As[chunk * 512 + lane * 8] = areg[cc];
      else      async16(gA + (size_t)chunk * 16 * K + k0, &As[chunk * 512]);
      async16(gB + (size_t)chunk * 16 * K + k0, &Bs[chunk * 512]);
    }
    __syncthreads();
    if (AF32 && k0 + 32 < K) {     // prefetch next A slab (overlaps with MFMA below)
#pragma unroll
      for (int cc = 0; cc < 2; ++cc) {
        const float* pa = (const float*)Ain +
            (size_t)(m0 + (wave*2 + cc)*16 + srow) * K + (k0 + 32) + scol;
        areg[cc] = pack8bf(((const float4*)pa)[0], ((const float4*)pa)[1]);
      }
    }
    short8 afr[4], bfr[4];
#pragma unroll
    for (int t = 0; t < 4; ++t) afr[t] = *(const short8*)&As[(wm + t*16 + c) * 32 + g * 8];
#pragma unroll
    for (int t = 0; t < 4; ++t) bfr[t] = *(const short8*)&Bs[(wn + t*16 + c) * 32 + g * 8];
#pragma unroll
    for (int i = 0; i < 4; ++i)
#pragma unroll
      for (int j = 0; j < 4; ++j)
        acc[i][j] = __builtin_amdgcn_mfma_f32_16x16x32_bf16(afr[i], bfr[j], acc[i][j], 0, 0, 0);
  }
  const bool vtrans = (!F32OUT) && (blockIdx.z == 2);
#pragma unroll
  for (int i = 0; i < 4; ++i) {
#pragma unroll
    for (int j = 0; j < 4; ++j) {
      const int m = m0 + wm + i*16 + g*4;
      const int n = n0 + wn + j*16 + c;
      if (vtrans) {
        bfu* vtp = (bfu*)C0 + (size_t)2 * strideC;
        size_t o = ((size_t)((m >> 11) * 16 + (n >> 6)) * 64 + (n & 63)) * Tsz + (m & 2047);
        *(short4v*)&vtp[o] = pack4bf(acc[i][j][0], acc[i][j][1], acc[i][j][2], acc[i][j][3]);
      } else {
#pragma unroll
        for (int r = 0; r < 4; ++r) {
          float v = acc[i][j][r] * scale;
          if (F32OUT) ((float*)C0)[(size_t)(m + r) * N + n] = v;
          else        ((bfu*)C0)[strideC * blockIdx.z + (size_t)(m + r) * N + n] = f2bf(v);
        }
      }
    }
  }
}

// ---------------- causal flash attention (S^T formulation, 64q x 128k tiles) ----------------
// Q,K natural [b*T+t][h*64+d]; V transposed as VT[b][h][d][t]. Q pre-scaled by log2e/8.
// grid (16, 32): block handles q-tiles {p, 31-p} of 64 rows (uniform 17-18 iters/block).
// 4 waves x 16 q-rows; 128-key tiles; single-buffer LDS (48KB -> 3 blocks/CU);
// next K/V tile prefetched into VGPRs right after the consume barrier.
__global__ __launch_bounds__(256, 2) void attn_kernel(const bfu* __restrict__ qkv,
                                                      bfu* __restrict__ obuf) {
  const int tid = threadIdx.x, wave = tid >> 6, lane = tid & 63;
  const int g = (lane >> 4) & 3, c = lane & 15, c7 = c & 7;
  const int bh = blockIdx.y, b = bh >> 4, h = bh & 15;
  const size_t hb = (size_t)b * Tsz * Dsz + h * 64;
  const bfu* Qp = qkv + hb;
  const bfu* Kp = qkv + (size_t)Msz * Dsz + hb;
  const bfu* Vt = qkv + (size_t)2 * Msz * Dsz + (size_t)bh * 64 * Tsz;

  __shared__ bfu Ks[128 * 64];      // [key][d], granule content XOR'd by key&7
  __shared__ bfu Vs[64 * 128];      // [d][key], granule content XOR'd by d&7
  __shared__ bfu Ps[4][16 * 128];   // per-wave [q][key], key-granules XOR q&7

  // staging coords: K chunk = 8 key-rows x 64 d (8 lanes/row); V chunk = 4 d-rows x 128 t
  const int krow_in = lane >> 3;                       // 0..7 (== global row & 7)
  const int kcol_g  = (((lane & 7) ^ krow_in) << 3);   // swizzled global d-col
  const int kcol_s  = ((lane & 7) << 3);               // plain LDS col
  const int vrow_in = lane >> 4;                       // 0..3
  const int vcol_s  = ((lane & 15) << 3);

  for (int half = 0; half < 2; ++half) {
    const int j = half ? (31 - (int)blockIdx.x) : (int)blockIdx.x;
    const int qw = j * 64 + wave * 16;
    const int ktm = j >> 1;

    short8 bq[2];                    // Q B-frags: n=q=qw+c, k=d
#pragma unroll
    for (int kk = 0; kk < 2; ++kk)
      bq[kk] = *(const short8*)(Qp + (size_t)(qw + c) * Dsz + kk * 32 + g * 8);

    floatx4 acc[4] = {};             // O: rows q=4g+r, cols d=nd*16+c
    float mi = -3.0e38f, li = 0.0f;  // state for q = qw + c (replicated over g)

    // preload kt=0 K/V chunks into regs
    short8 kreg[4], vreg[4];
#pragma unroll
    for (int cc = 0; cc < 4; ++cc) {
      const int ch = wave * 4 + cc;
      kreg[cc] = *(const short8*)(Kp + (size_t)(ch * 8 + krow_in) * Dsz + kcol_g);
      const int drow = ch * 4 + vrow_in;
      vreg[cc] = *(const short8*)(Vt + (size_t)drow * Tsz + (((lane & 15) ^ (drow & 7)) << 3));
    }

    for (int kt = 0; kt <= ktm; ++kt) {
      __syncthreads();               // prior iter's LDS reads complete
#pragma unroll
      for (int cc = 0; cc < 4; ++cc) {
        const int ch = wave * 4 + cc;
        *(short8*)&Ks[(ch * 8 + krow_in) * 64 + kcol_s] = kreg[cc];
        const int drow = ch * 4 + vrow_in;
        *(short8*)&Vs[drow * 128 + vcol_s] = vreg[cc];
      }
      __syncthreads();               // staged tile visible
      if (kt < ktm) {                // prefetch next tile into regs (overlaps compute)
#pragma unroll
        for (int cc = 0; cc < 4; ++cc) {
          const int ch = wave * 4 + cc;
          kreg[cc] = *(const short8*)(Kp + (size_t)((kt+1)*128 + ch*8 + krow_in) * Dsz + kcol_g);
          const int drow = ch * 4 + vrow_in;
          vreg[cc] = *(const short8*)(Vt + (size_t)drow * Tsz + (kt+1)*128 +
                                      (((lane & 15) ^ (drow & 7)) << 3));
        }
      }

      // S^T[key][q] = K * Q^T
      floatx4 st[8] = {};
#pragma unroll
      for (int kk = 0; kk < 2; ++kk)
#pragma unroll
        for (int mk = 0; mk < 8; ++mk) {
          const short8 kf = *(const short8*)&Ks[(mk * 16 + c) * 64 + (((kk * 4 + g) ^ c7) << 3)];
          st[mk] = __builtin_amdgcn_mfma_f32_16x16x32_bf16(kf, bq[kk], st[mk], 0, 0, 0);
        }

      if (kt == ktm) {                 // causal mask (diagonal tile only)
#pragma unroll
        for (int mk = 0; mk < 8; ++mk) {
          const int keyb = kt * 128 + mk * 16 + g * 4;
#pragma unroll
          for (int r = 0; r < 4; ++r)
            if (keyb + r > qw + c) st[mk][r] = -1.0e38f;
        }
      }

      // online softmax over this tile's 128 keys (per lane: q = qw+c)
      float mloc = -3.0e38f;
#pragma unroll
      for (int mk = 0; mk < 8; ++mk)
#pragma unroll
        for (int r = 0; r < 4; ++r) mloc = fmaxf(mloc, st[mk][r]);
      mloc = fmaxf(mloc, __shfl_xor(mloc, 16));
      mloc = fmaxf(mloc, __shfl_xor(mloc, 32));
      const float mnew = fmaxf(mi, mloc);
      const float alpha = exp2f(mi - mnew);
      mi = mnew;
      float sum = 0.0f;
#pragma unroll
      for (int mk = 0; mk < 8; ++mk) {
        float pr[4];
#pragma unroll
        for (int r = 0; r < 4; ++r) { pr[r] = exp2f(st[mk][r] - mnew); sum += pr[r]; }
        *(short4v*)&Ps[wave][c * 128 + (((mk * 2 + (g >> 1)) ^ c7) << 3) + ((g & 1) << 2)] =
            pack4bf(pr[0], pr[1], pr[2], pr[3]);
      }
      sum += __shfl_xor(sum, 16);
      sum += __shfl_xor(sum, 32);
      li = li * alpha + sum;

      float al[4];
#pragma unroll
      for (int r = 0; r < 4; ++r) al[r] = __shfl(alpha, (lane & 48) | (g * 4 + r));
#pragma unroll
      for (int nd = 0; nd < 4; ++nd)
#pragma unroll
        for (int r = 0; r < 4; ++r) acc[nd][r] *= al[r];

      // O += P * V
#pragma unroll
      for (int kc = 0; kc < 4; ++kc) {
        const int sl = ((kc * 4 + g) ^ c7) << 3;
        const short8 pf = *(const short8*)&Ps[wave][c * 128 + sl];
#pragma unroll
        for (int nd = 0; nd < 4; ++nd) {
          const short8 vf = *(const short8*)&Vs[(nd * 16 + c) * 128 + sl];
          acc[nd] = __builtin_amdgcn_mfma_f32_16x16x32_bf16(pf, vf, acc[nd], 0, 0, 0);
        }
      }
    }

    // epilogue: O / l
    float inv[4];
#pragma unroll
    for (int r = 0; r < 4; ++r) inv[r] = 1.0f / __shfl(li, (lane & 48) | (g * 4 + r));
#pragma unroll
    for (int nd = 0; nd < 4; ++nd)
#pragma unroll
      for (int r = 0; r < 4; ++r)
        obuf[(size_t)(b * Tsz + qw + g * 4 + r) * Dsz + h * 64 + nd * 16 + c] =
            f2bf(acc[nd][r] * inv[r]);
  }
}

extern "C" void kernel_launch(void* const* d_in, const int* in_sizes, int n_in,
                              void* d_out, int out_size, void* d_ws, size_t ws_size,
                              hipStream_t stream) {
  const float* x  = (const float*)d_in[0];
  const float* Wq = (const float*)d_in[1];
  const float* Wk = (const float*)d_in[2];
  const float* Wv = (const float*)d_in[3];
  const float* Wo = (const float*)d_in[4];
  float* out = (float*)d_out;

  // workspace (bf16 elems): wt 4x1M | qkv 3x4M (Q,K natural; slot 2 = VT) | obuf 4M = 40 MiB
  bfu* wt   = (bfu*)d_ws;
  bfu* qkv  = wt  + (size_t)4 * Dsz * Dsz;
  bfu* obuf = qkv + (size_t)3 * Msz * Dsz;

  transpose_w<<<dim3(32, 32, 4), dim3(32, 8), 0, stream>>>(Wq, Wk, Wv, Wo, wt);
  // QKV projections, x converted in-GEMM; Q scaled by log2(e)/sqrt(64); V written transposed
  gemm128<false, true><<<dim3(Dsz / 128, Msz / 128, 3), dim3(256), 0, stream>>>(
      (const void*)x, wt, (void*)qkv, Dsz, Dsz, (size_t)Dsz * Dsz, (size_t)Msz * Dsz,
      0.125f * 1.44269504088896f);
  attn_kernel<<<dim3(16, Bsz * NHsz), dim3(256), 0, stream>>>(qkv, obuf);
  // output projection -> fp32 d_out
  gemm128<true, false><<<dim3(Dsz / 128, Msz / 128, 1), dim3(256), 0, stream>>>(
      (const void*)obuf, wt + (size_t)3 * Dsz * Dsz, (void*)out, Dsz, Dsz,
      (size_t)0, (size_t)0, 1.0f);
}

// Round 6
// 202.613 us; speedup vs baseline: 1.0987x; 1.0408x over previous
//
#include <hip/hip_runtime.h>
#include <hip/hip_bf16.h>
#include <string.h>

#define Bsz 2
#define Tsz 2048
#define Dsz 1024
#define NHsz 16
#define Msz (Bsz*Tsz)  // 4096 rows total

typedef unsigned short bfu;  // bf16 bit pattern
typedef __attribute__((ext_vector_type(8))) short short8;   // MFMA A/B frag: 8 bf16
typedef __attribute__((ext_vector_type(4))) short short4v;
typedef __attribute__((ext_vector_type(4))) float floatx4;  // MFMA C/D frag

__device__ __forceinline__ bfu f2bf(float f) {
  unsigned int u = __builtin_bit_cast(unsigned int, f);
  u += 0x7fffu + ((u >> 16) & 1u);
  return (bfu)(u >> 16);
}

__device__ __forceinline__ short4v pack4bf(float a, float b, float c_, float d) {
  // v_cvt_pk_bf16_f32: 2 ops for 4 values
  __hip_bfloat162 h01 = __float22bfloat162_rn(make_float2(a, b));
  __hip_bfloat162 h23 = __float22bfloat162_rn(make_float2(c_, d));
  uint2 uu;
  memcpy(&uu.x, &h01, 4);
  memcpy(&uu.y, &h23, 4);
  return __builtin_bit_cast(short4v, uu);
}

__device__ __forceinline__ short8 pack8bf(float4 a, float4 b) {
  __hip_bfloat162 h0 = __float22bfloat162_rn(make_float2(a.x, a.y));
  __hip_bfloat162 h1 = __float22bfloat162_rn(make_float2(a.z, a.w));
  __hip_bfloat162 h2 = __float22bfloat162_rn(make_float2(b.x, b.y));
  __hip_bfloat162 h3 = __float22bfloat162_rn(make_float2(b.z, b.w));
  uint4 u;
  memcpy(&u.x, &h0, 4); memcpy(&u.y, &h1, 4);
  memcpy(&u.z, &h2, 4); memcpy(&u.w, &h3, 4);
  return __builtin_bit_cast(short8, u);
}

__device__ __forceinline__ void async16(const void* g, void* l) {
  void* gnc = (void*)g;
  __builtin_amdgcn_global_load_lds((__attribute__((address_space(1))) void*)gnc,
                                   (__attribute__((address_space(3))) void*)l,
                                   16, 0, 0);
}

// ---------------- W (KxN fp32) -> WT (NxK bf16), z = 4 weights ----------------
__global__ __launch_bounds__(256) void transpose_w(const float* __restrict__ W0, const float* __restrict__ W1,
                                                   const float* __restrict__ W2, const float* __restrict__ W3,
                                                   bfu* __restrict__ wt) {
  __shared__ float tile[32][33];
  const float* W = blockIdx.z == 0 ? W0 : blockIdx.z == 1 ? W1 : blockIdx.z == 2 ? W2 : W3;
  bfu* WT = wt + (size_t)blockIdx.z * Dsz * Dsz;
  int tx = threadIdx.x, ty = threadIdx.y;           // 32 x 8
  int kb = blockIdx.y * 32, nb = blockIdx.x * 32;
#pragma unroll
  for (int i = 0; i < 4; ++i)
    tile[ty + i*8][tx] = W[(size_t)(kb + ty + i*8) * Dsz + nb + tx];
  __syncthreads();
#pragma unroll
  for (int i = 0; i < 4; ++i)
    WT[(size_t)(nb + ty + i*8) * Dsz + kb + tx] = f2bf(tile[tx][ty + i*8]);
}

// ---------------- 128xNT bf16 MFMA GEMM: C = A(MxK) * BT(NxK)^T ----------------
// AF32: A fp32, converted in-regs (software-pipelined). z==0: scale0 (Q path).
// z==2 (NT=128, bf16 out): V written transposed VT[b][h][d][t] via LDS-coalesced epilogue.
template <bool F32OUT, bool AF32, int NT>
__global__ __launch_bounds__(256) void gemm128(const void* __restrict__ Ain, const bfu* __restrict__ Bt0,
                                               void* __restrict__ C0, int K, int N,
                                               size_t strideB, size_t strideC, float scale0) {
  constexpr int NJ = NT / 32;                       // n-frags per wave
  const int tid = threadIdx.x, wave = tid >> 6, lane = tid & 63;
  const int g = lane >> 4, c = lane & 15;
  const int m0 = blockIdx.y * 128, n0 = blockIdx.x * NT;
  const bfu* Bt = Bt0 + strideB * blockIdx.z;
  const float scale = (blockIdx.z == 0) ? scale0 : 1.0f;
  __shared__ bfu smem[4096 + NT * 32];              // As | Bs (also VT-transpose buf)
  bfu* As = smem;
  bfu* Bs = smem + 4096;
  floatx4 acc[4][NJ] = {};
  const int srow = lane >> 2, scol = (lane & 3) * 8;
  const bfu* gB = Bt + (size_t)(n0 + srow) * K + scol;
  const int wm = (wave >> 1) * 64, wn = (wave & 1) * (NT / 2);

  short8 areg[2];
  if (AF32) {   // preload k0=0 A-chunks as fp32, convert in regs
#pragma unroll
    for (int cc = 0; cc < 2; ++cc) {
      const float* pa = (const float*)Ain +
          (size_t)(m0 + (wave*2 + cc)*16 + srow) * K + scol;
      areg[cc] = pack8bf(((const float4*)pa)[0], ((const float4*)pa)[1]);
    }
  }
  const bfu* gA = AF32 ? nullptr : (const bfu*)Ain + (size_t)(m0 + srow) * K + scol;

  for (int k0 = 0; k0 < K; k0 += 32) {
    __syncthreads();               // prior reads done before overwrite
#pragma unroll
    for (int cc = 0; cc < 2; ++cc) {
      const int chunk = wave * 2 + cc;
      if (AF32) *(short8*)&As[chunk * 512 + lane * 8] = areg[cc];
      else      async16(gA + (size_t)chunk * 16 * K + k0, &As[chunk * 512]);
    }
#pragma unroll
    for (int cc = 0; cc < NT/64; ++cc) {
      const int chunk = wave * (NT/64) + cc;
      async16(gB + (size_t)chunk * 16 * K + k0, &Bs[chunk * 512]);
    }
    __syncthreads();
    if (AF32 && k0 + 32 < K) {     // prefetch next A slab (overlaps with MFMA below)
#pragma unroll
      for (int cc = 0; cc < 2; ++cc) {
        const float* pa = (const float*)Ain +
            (size_t)(m0 + (wave*2 + cc)*16 + srow) * K + (k0 + 32) + scol;
        areg[cc] = pack8bf(((const float4*)pa)[0], ((const float4*)pa)[1]);
      }
    }
    short8 afr[4], bfr[NJ];
#pragma unroll
    for (int t = 0; t < 4; ++t) afr[t] = *(const short8*)&As[(wm + t*16 + c) * 32 + g * 8];
#pragma unroll
    for (int t = 0; t < NJ; ++t) bfr[t] = *(const short8*)&Bs[(wn + t*16 + c) * 32 + g * 8];
#pragma unroll
    for (int i = 0; i < 4; ++i)
#pragma unroll
      for (int j = 0; j < NJ; ++j)
        acc[i][j] = __builtin_amdgcn_mfma_f32_16x16x32_bf16(afr[i], bfr[j], acc[i][j], 0, 0, 0);
  }

  const bool vtrans = (!F32OUT) && (NT == 128) && (blockIdx.z == 2);
  if (vtrans) {
    // LDS-coalesced transpose: 2 passes of 64 n-cols (= one head each) x 128 m.
    bfu* vtp = (bfu*)C0 + (size_t)2 * strideC;
#pragma unroll
    for (int p = 0; p < 2; ++p) {
      __syncthreads();             // As/Bs reads (or prior pass stores) complete
      if ((wave & 1) == p) {       // waves holding n-cols [p*64, p*64+64)
#pragma unroll
        for (int i = 0; i < 4; ++i)
#pragma unroll
          for (int j = 0; j < NJ; ++j) {
            const int nl = j*16 + c;                      // 0..63 within pass
            const int mg = ((wm + i*16) >> 3) + (g >> 1); // m-granule of 8
            const int phys = nl * 128 + ((mg ^ (nl & 15)) << 3) + ((g & 1) << 2);
            *(short4v*)&smem[phys] = pack4bf(acc[i][j][0], acc[i][j][1],
                                             acc[i][j][2], acc[i][j][3]);
          }
      }
      __syncthreads();
      const int h_ = (n0 + p * 64) >> 6;
      bfu* dst = vtp + ((size_t)((m0 >> 11) * 16 + h_) * 64) * Tsz + (m0 & 2047);
#pragma unroll
      for (int s = 0; s < 4; ++s) {
        const int nl = s * 16 + (tid >> 4);
        const int me = (tid & 15) << 3;
        const int phys = nl * 128 + (((me >> 3) ^ (nl & 15)) << 3);
        *(short8*)&dst[(size_t)nl * Tsz + me] = *(const short8*)&smem[phys];
      }
    }
    return;
  }

#pragma unroll
  for (int i = 0; i < 4; ++i) {
#pragma unroll
    for (int j = 0; j < NJ; ++j) {
      const int m = m0 + wm + i*16 + g*4;
      const int n = n0 + wn + j*16 + c;
#pragma unroll
      for (int r = 0; r < 4; ++r) {
        float v = acc[i][j][r] * scale;
        if (F32OUT) ((float*)C0)[(size_t)(m + r) * N + n] = v;
        else        ((bfu*)C0)[strideC * blockIdx.z + (size_t)(m + r) * N + n] = f2bf(v);
      }
    }
  }
}

// ---------------- causal flash attention (S^T formulation) ----------------
// Q,K natural [b*T+t][h*64+d]; V transposed at qkv+2*M*D as VT[b][h][d][t].
// Q pre-scaled by log2e/sqrt(DH). grid (16, 32): block handles q-tiles {p, 31-p} of
// 64 rows; 4 waves x 16 q-rows each; 128-key tiles; XOR-swizzled LDS, async staging.
__global__ __launch_bounds__(256, 2) void attn_kernel(const bfu* __restrict__ qkv,
                                                      bfu* __restrict__ obuf) {
  const int tid = threadIdx.x, wave = tid >> 6, lane = tid & 63;
  const int g = (lane >> 4) & 3, c = lane & 15, c7 = c & 7;
  const int bh = blockIdx.y, b = bh >> 4, h = bh & 15;
  const size_t hb = (size_t)b * Tsz * Dsz + h * 64;
  const bfu* Qp = qkv + hb;
  const bfu* Kp = qkv + (size_t)Msz * Dsz + hb;
  const bfu* Vt = qkv + (size_t)2 * Msz * Dsz + (size_t)bh * 64 * Tsz;

  __shared__ bfu Ks[128 * 64];      // [key][d], d-granules XOR key&7
  __shared__ bfu Vs[64 * 128];      // [d][key], key-granules XOR d&7
  __shared__ bfu Ps[4][16 * 128];   // per-wave [q][key], key-granules XOR q&7

  const int kst_row = lane >> 3;                    // K staging: 8 lanes/key-row
  const int kst_off = ((lane & 7) ^ kst_row) << 3;
  const int vst_row = lane >> 4;                    // V staging: 16 lanes/d-row

  for (int half = 0; half < 2; ++half) {
    const int j = half ? (31 - (int)blockIdx.x) : (int)blockIdx.x;
    const int qw = j * 64 + wave * 16;
    const int ktm = j >> 1;

    short8 bq[2];                    // Q B-frags: n=q=qw+c, k=d
#pragma unroll
    for (int kk = 0; kk < 2; ++kk)
      bq[kk] = *(const short8*)(Qp + (size_t)(qw + c) * Dsz + kk * 32 + g * 8);

    floatx4 acc[4] = {};             // O: rows q=4g+r, cols d=nd*16+c
    float mi = -3.0e38f, li = 0.0f;  // state for q = qw + c (replicated over g)

    for (int kt = 0; kt <= ktm; ++kt) {
      __syncthreads();
#pragma unroll
      for (int cc = 0; cc < 4; ++cc) {     // stage 4 K-chunks + 4 V-chunks per wave
        const int ch = wave * 4 + cc;
        async16(Kp + (size_t)(kt * 128 + ch * 8 + kst_row) * Dsz + kst_off, &Ks[ch * 512]);
        const int drow = ch * 4 + vst_row;
        async16(Vt + (size_t)drow * Tsz + kt * 128 + (((lane & 15) ^ (drow & 7)) << 3), &Vs[ch * 512]);
      }
      __syncthreads();

      // S^T[key][q] = K * Q^T
      floatx4 st[8] = {};
#pragma unroll
      for (int kk = 0; kk < 2; ++kk)
#pragma unroll
        for (int mk = 0; mk < 8; ++mk) {
          const short8 kf = *(const short8*)&Ks[(mk * 16 + c) * 64 + (((kk * 4 + g) ^ c7) << 3)];
          st[mk] = __builtin_amdgcn_mfma_f32_16x16x32_bf16(kf, bq[kk], st[mk], 0, 0, 0);
        }

      if (kt == ktm) {                 // causal mask (diagonal tile only)
#pragma unroll
        for (int mk = 0; mk < 8; ++mk) {
          const int keyb = kt * 128 + mk * 16 + g * 4;
#pragma unroll
          for (int r = 0; r < 4; ++r)
            if (keyb + r > qw + c) st[mk][r] = -1.0e38f;
        }
      }

      // online softmax over this tile's 128 keys (per lane: q = qw+c)
      float mloc = -3.0e38f;
#pragma unroll
      for (int mk = 0; mk < 8; ++mk)
#pragma unroll
        for (int r = 0; r < 4; ++r) mloc = fmaxf(mloc, st[mk][r]);
      mloc = fmaxf(mloc, __shfl_xor(mloc, 16));
      mloc = fmaxf(mloc, __shfl_xor(mloc, 32));
      const float mnew = fmaxf(mi, mloc);
      const float alpha = exp2f(mi - mnew);
      mi = mnew;
      float sum = 0.0f;
#pragma unroll
      for (int mk = 0; mk < 8; ++mk) {
        float pr[4];
#pragma unroll
        for (int r = 0; r < 4; ++r) { pr[r] = exp2f(st[mk][r] - mnew); sum += pr[r]; }
        *(short4v*)&Ps[wave][c * 128 + (((mk * 2 + (g >> 1)) ^ c7) << 3) + ((g & 1) << 2)] =
            pack4bf(pr[0], pr[1], pr[2], pr[3]);
      }
      sum += __shfl_xor(sum, 16);
      sum += __shfl_xor(sum, 32);
      li = li * alpha + sum;

      float al[4];
#pragma unroll
      for (int r = 0; r < 4; ++r) al[r] = __shfl(alpha, (lane & 48) | (g * 4 + r));
#pragma unroll
      for (int nd = 0; nd < 4; ++nd)
#pragma unroll
        for (int r = 0; r < 4; ++r) acc[nd][r] *= al[r];

      // O += P * V
#pragma unroll
      for (int kc = 0; kc < 4; ++kc) {
        const int sl = ((kc * 4 + g) ^ c7) << 3;
        const short8 pf = *(const short8*)&Ps[wave][c * 128 + sl];
#pragma unroll
        for (int nd = 0; nd < 4; ++nd) {
          const short8 vf = *(const short8*)&Vs[(nd * 16 + c) * 128 + sl];
          acc[nd] = __builtin_amdgcn_mfma_f32_16x16x32_bf16(pf, vf, acc[nd], 0, 0, 0);
        }
      }
    }

    // epilogue: O / l
    float inv[4];
#pragma unroll
    for (int r = 0; r < 4; ++r) inv[r] = 1.0f / __shfl(li, (lane & 48) | (g * 4 + r));
#pragma unroll
    for (int nd = 0; nd < 4; ++nd)
#pragma unroll
      for (int r = 0; r < 4; ++r)
        obuf[(size_t)(b * Tsz + qw + g * 4 + r) * Dsz + h * 64 + nd * 16 + c] =
            f2bf(acc[nd][r] * inv[r]);
  }
}

extern "C" void kernel_launch(void* const* d_in, const int* in_sizes, int n_in,
                              void* d_out, int out_size, void* d_ws, size_t ws_size,
                              hipStream_t stream) {
  const float* x  = (const float*)d_in[0];
  const float* Wq = (const float*)d_in[1];
  const float* Wk = (const float*)d_in[2];
  const float* Wv = (const float*)d_in[3];
  const float* Wo = (const float*)d_in[4];
  float* out = (float*)d_out;

  // workspace (bf16 elems): wt 4x1M | qkv 3x4M (Q,K natural; slot 2 = VT) | obuf 4M = 40 MiB
  bfu* wt   = (bfu*)d_ws;
  bfu* qkv  = wt  + (size_t)4 * Dsz * Dsz;
  bfu* obuf = qkv + (size_t)3 * Msz * Dsz;

  transpose_w<<<dim3(32, 32, 4), dim3(32, 8), 0, stream>>>(Wq, Wk, Wv, Wo, wt);
  // QKV projections, x converted in-GEMM; Q scaled by log2(e)/sqrt(64); V -> VT (z==2)
  gemm128<false, true, 128><<<dim3(Dsz / 128, Msz / 128, 3), dim3(256), 0, stream>>>(
      (const void*)x, wt, (void*)qkv, Dsz, Dsz, (size_t)Dsz * Dsz, (size_t)Msz * Dsz,
      0.125f * 1.44269504088896f);
  attn_kernel<<<dim3(16, Bsz * NHsz), dim3(256), 0, stream>>>(qkv, obuf);
  // output projection -> fp32 d_out (128x64 tiles: 512 blocks = 2/CU)
  gemm128<true, false, 64><<<dim3(Dsz / 64, Msz / 128, 1), dim3(256), 0, stream>>>(
      (const void*)obuf, wt + (size_t)3 * Dsz * Dsz, (void*)out, Dsz, Dsz,
      (size_t)0, (size_t)0, 1.0f);
}

// Round 7
// 198.894 us; speedup vs baseline: 1.1193x; 1.0187x over previous
//
#include <hip/hip_runtime.h>
#include <hip/hip_bf16.h>
#include <string.h>

#define Bsz 2
#define Tsz 2048
#define Dsz 1024
#define NHsz 16
#define Msz (Bsz*Tsz)  // 4096 rows total

typedef unsigned short bfu;  // bf16 bit pattern
typedef __attribute__((ext_vector_type(8))) short short8;   // MFMA A/B frag: 8 bf16
typedef __attribute__((ext_vector_type(4))) short short4v;
typedef __attribute__((ext_vector_type(4))) float floatx4;  // MFMA C/D frag

__device__ __forceinline__ bfu f2bf(float f) {
  unsigned int u = __builtin_bit_cast(unsigned int, f);
  u += 0x7fffu + ((u >> 16) & 1u);
  return (bfu)(u >> 16);
}

__device__ __forceinline__ short4v pack4bf(float a, float b, float c_, float d) {
  // v_cvt_pk_bf16_f32: 2 ops for 4 values (GEMM epilogues only — A/B'd out of attn)
  __hip_bfloat162 h01 = __float22bfloat162_rn(make_float2(a, b));
  __hip_bfloat162 h23 = __float22bfloat162_rn(make_float2(c_, d));
  uint2 uu;
  memcpy(&uu.x, &h01, 4);
  memcpy(&uu.y, &h23, 4);
  return __builtin_bit_cast(short4v, uu);
}

__device__ __forceinline__ short8 pack8bf(float4 a, float4 b) {
  __hip_bfloat162 h0 = __float22bfloat162_rn(make_float2(a.x, a.y));
  __hip_bfloat162 h1 = __float22bfloat162_rn(make_float2(a.z, a.w));
  __hip_bfloat162 h2 = __float22bfloat162_rn(make_float2(b.x, b.y));
  __hip_bfloat162 h3 = __float22bfloat162_rn(make_float2(b.z, b.w));
  uint4 u;
  memcpy(&u.x, &h0, 4); memcpy(&u.y, &h1, 4);
  memcpy(&u.z, &h2, 4); memcpy(&u.w, &h3, 4);
  return __builtin_bit_cast(short8, u);
}

__device__ __forceinline__ void async16(const void* g, void* l) {
  void* gnc = (void*)g;
  __builtin_amdgcn_global_load_lds((__attribute__((address_space(1))) void*)gnc,
                                   (__attribute__((address_space(3))) void*)l,
                                   16, 0, 0);
}

// ---------------- W (KxN fp32) -> WT (NxK bf16), z = 4 weights ----------------
// z==0 (Wq) pre-scaled by log2e/sqrt(DH) so the GEMM epilogue needs no scale.
__global__ __launch_bounds__(256) void transpose_w(const float* __restrict__ W0, const float* __restrict__ W1,
                                                   const float* __restrict__ W2, const float* __restrict__ W3,
                                                   bfu* __restrict__ wt) {
  __shared__ float tile[32][33];
  const float* W = blockIdx.z == 0 ? W0 : blockIdx.z == 1 ? W1 : blockIdx.z == 2 ? W2 : W3;
  const float s = (blockIdx.z == 0) ? 0.18033688011112042f : 1.0f;  // 0.125*log2(e)
  bfu* WT = wt + (size_t)blockIdx.z * Dsz * Dsz;
  int tx = threadIdx.x, ty = threadIdx.y;           // 32 x 8
  int kb = blockIdx.y * 32, nb = blockIdx.x * 32;
#pragma unroll
  for (int i = 0; i < 4; ++i)
    tile[ty + i*8][tx] = W[(size_t)(kb + ty + i*8) * Dsz + nb + tx];
  __syncthreads();
#pragma unroll
  for (int i = 0; i < 4; ++i)
    WT[(size_t)(nb + ty + i*8) * Dsz + kb + tx] = f2bf(tile[tx][ty + i*8] * s);
}

// ---------------- 128xNT bf16 MFMA GEMM: C = A(MxK) * BT(NxK)^T ----------------
// AF32: A fp32, converted in-regs (software-pipelined).
// z==2 (NT=128, bf16 out): V written transposed VT[b][h][d][t] via LDS-coalesced epilogue.
template <bool F32OUT, bool AF32, int NT>
__global__ __launch_bounds__(256) void gemm128(const void* __restrict__ Ain, const bfu* __restrict__ Bt0,
                                               void* __restrict__ C0, int K, int N,
                                               size_t strideB, size_t strideC) {
  constexpr int NJ = NT / 32;                       // n-frags per wave
  const int tid = threadIdx.x, wave = tid >> 6, lane = tid & 63;
  const int g = lane >> 4, c = lane & 15;
  const int m0 = blockIdx.y * 128, n0 = blockIdx.x * NT;
  const bfu* Bt = Bt0 + strideB * blockIdx.z;
  __shared__ bfu smem[4096 + NT * 32];              // As | Bs (also VT-transpose buf)
  bfu* As = smem;
  bfu* Bs = smem + 4096;
  floatx4 acc[4][NJ] = {};
  const int srow = lane >> 2, scol = (lane & 3) * 8;
  const bfu* gB = Bt + (size_t)(n0 + srow) * K + scol;
  const int wm = (wave >> 1) * 64, wn = (wave & 1) * (NT / 2);

  short8 areg[2];
  if (AF32) {   // preload k0=0 A-chunks as fp32, convert in regs
#pragma unroll
    for (int cc = 0; cc < 2; ++cc) {
      const float* pa = (const float*)Ain +
          (size_t)(m0 + (wave*2 + cc)*16 + srow) * K + scol;
      areg[cc] = pack8bf(((const float4*)pa)[0], ((const float4*)pa)[1]);
    }
  }
  const bfu* gA = AF32 ? nullptr : (const bfu*)Ain + (size_t)(m0 + srow) * K + scol;

  for (int k0 = 0; k0 < K; k0 += 32) {
    __syncthreads();               // prior reads done before overwrite
#pragma unroll
    for (int cc = 0; cc < 2; ++cc) {
      const int chunk = wave * 2 + cc;
      if (AF32) *(short8*)&As[chunk * 512 + lane * 8] = areg[cc];
      else      async16(gA + (size_t)chunk * 16 * K + k0, &As[chunk * 512]);
    }
#pragma unroll
    for (int cc = 0; cc < NT/64; ++cc) {
      const int chunk = wave * (NT/64) + cc;
      async16(gB + (size_t)chunk * 16 * K + k0, &Bs[chunk * 512]);
    }
    __syncthreads();
    if (AF32 && k0 + 32 < K) {     // prefetch next A slab (overlaps with MFMA below)
#pragma unroll
      for (int cc = 0; cc < 2; ++cc) {
        const float* pa = (const float*)Ain +
            (size_t)(m0 + (wave*2 + cc)*16 + srow) * K + (k0 + 32) + scol;
        areg[cc] = pack8bf(((const float4*)pa)[0], ((const float4*)pa)[1]);
      }
    }
    short8 afr[4], bfr[NJ];
#pragma unroll
    for (int t = 0; t < 4; ++t) afr[t] = *(const short8*)&As[(wm + t*16 + c) * 32 + g * 8];
#pragma unroll
    for (int t = 0; t < NJ; ++t) bfr[t] = *(const short8*)&Bs[(wn + t*16 + c) * 32 + g * 8];
#pragma unroll
    for (int i = 0; i < 4; ++i)
#pragma unroll
      for (int j = 0; j < NJ; ++j)
        acc[i][j] = __builtin_amdgcn_mfma_f32_16x16x32_bf16(afr[i], bfr[j], acc[i][j], 0, 0, 0);
  }

  const bool vtrans = (!F32OUT) && (NT == 128) && (blockIdx.z == 2);
  if (vtrans) {
    // LDS-coalesced transpose: 2 passes of 64 n-cols (= one head each) x 128 m.
    bfu* vtp = (bfu*)C0 + (size_t)2 * strideC;
#pragma unroll
    for (int p = 0; p < 2; ++p) {
      __syncthreads();             // As/Bs reads (or prior pass stores) complete
      if ((wave & 1) == p) {       // waves holding n-cols [p*64, p*64+64)
#pragma unroll
        for (int i = 0; i < 4; ++i)
#pragma unroll
          for (int j = 0; j < NJ; ++j) {
            const int nl = j*16 + c;                      // 0..63 within pass
            const int mg = ((wm + i*16) >> 3) + (g >> 1); // m-granule of 8
            const int phys = nl * 128 + ((mg ^ (nl & 15)) << 3) + ((g & 1) << 2);
            *(short4v*)&smem[phys] = pack4bf(acc[i][j][0], acc[i][j][1],
                                             acc[i][j][2], acc[i][j][3]);
          }
      }
      __syncthreads();
      const int h_ = (n0 + p * 64) >> 6;
      bfu* dst = vtp + ((size_t)((m0 >> 11) * 16 + h_) * 64) * Tsz + (m0 & 2047);
#pragma unroll
      for (int s = 0; s < 4; ++s) {
        const int nl = s * 16 + (tid >> 4);
        const int me = (tid & 15) << 3;
        const int phys = nl * 128 + (((me >> 3) ^ (nl & 15)) << 3);
        *(short8*)&dst[(size_t)nl * Tsz + me] = *(const short8*)&smem[phys];
      }
    }
    return;
  }

#pragma unroll
  for (int i = 0; i < 4; ++i) {
#pragma unroll
    for (int j = 0; j < NJ; ++j) {
      const int m = m0 + wm + i*16 + g*4;
      const int n = n0 + wn + j*16 + c;
#pragma unroll
      for (int r = 0; r < 4; ++r) {
        float v = acc[i][j][r];
        if (F32OUT) ((float*)C0)[(size_t)(m + r) * N + n] = v;
        else        ((bfu*)C0)[strideC * blockIdx.z + (size_t)(m + r) * N + n] = f2bf(v);
      }
    }
  }
}

// ---------------- causal flash attention (S^T formulation) ----------------
// Q,K natural [b*T+t][h*64+d]; V transposed at qkv+2*M*D as VT[b][h][d][t].
// Q pre-scaled by log2e/sqrt(DH) (folded into Wq). grid (16, 32): block handles
// q-tiles {p, 31-p} of 64 rows; 4 waves x 16 q-rows; 128-key tiles; XOR-swizzled LDS.
__global__ __launch_bounds__(256, 2) void attn_kernel(const bfu* __restrict__ qkv,
                                                      bfu* __restrict__ obuf) {
  const int tid = threadIdx.x, wave = tid >> 6, lane = tid & 63;
  const int g = (lane >> 4) & 3, c = lane & 15, c7 = c & 7;
  const int bh = blockIdx.y, b = bh >> 4, h = bh & 15;
  const size_t hb = (size_t)b * Tsz * Dsz + h * 64;
  const bfu* Qp = qkv + hb;
  const bfu* Kp = qkv + (size_t)Msz * Dsz + hb;
  const bfu* Vt = qkv + (size_t)2 * Msz * Dsz + (size_t)bh * 64 * Tsz;

  __shared__ bfu Ks[128 * 64];      // [key][d], d-granules XOR key&7
  __shared__ bfu Vs[64 * 128];      // [d][key], key-granules XOR d&7
  __shared__ bfu Ps[4][16 * 128];   // per-wave [q][key], key-granules XOR q&7

  const int kst_row = lane >> 3;                    // K staging: 8 lanes/key-row
  const int kst_off = ((lane & 7) ^ kst_row) << 3;
  const int vst_row = lane >> 4;                    // V staging: 16 lanes/d-row

  for (int half = 0; half < 2; ++half) {
    const int j = half ? (31 - (int)blockIdx.x) : (int)blockIdx.x;
    const int qw = j * 64 + wave * 16;
    const int ktm = j >> 1;

    short8 bq[2];                    // Q B-frags: n=q=qw+c, k=d
#pragma unroll
    for (int kk = 0; kk < 2; ++kk)
      bq[kk] = *(const short8*)(Qp + (size_t)(qw + c) * Dsz + kk * 32 + g * 8);

    floatx4 acc[4] = {};             // O: rows q=4g+r, cols d=nd*16+c
    float mi = -3.0e38f, li = 0.0f;  // state for q = qw + c (replicated over g)

    for (int kt = 0; kt <= ktm; ++kt) {
      __syncthreads();
#pragma unroll
      for (int cc = 0; cc < 4; ++cc) {     // stage 4 K-chunks + 4 V-chunks per wave
        const int ch = wave * 4 + cc;
        async16(Kp + (size_t)(kt * 128 + ch * 8 + kst_row) * Dsz + kst_off, &Ks[ch * 512]);
        const int drow = ch * 4 + vst_row;
        async16(Vt + (size_t)drow * Tsz + kt * 128 + (((lane & 15) ^ (drow & 7)) << 3), &Vs[ch * 512]);
      }
      __syncthreads();

      // S^T[key][q] = K * Q^T
      floatx4 st[8] = {};
#pragma unroll
      for (int kk = 0; kk < 2; ++kk)
#pragma unroll
        for (int mk = 0; mk < 8; ++mk) {
          const short8 kf = *(const short8*)&Ks[(mk * 16 + c) * 64 + (((kk * 4 + g) ^ c7) << 3)];
          st[mk] = __builtin_amdgcn_mfma_f32_16x16x32_bf16(kf, bq[kk], st[mk], 0, 0, 0);
        }

      if (kt == ktm) {                 // causal mask (diagonal tile only)
#pragma unroll
        for (int mk = 0; mk < 8; ++mk) {
          const int keyb = kt * 128 + mk * 16 + g * 4;
#pragma unroll
          for (int r = 0; r < 4; ++r)
            if (keyb + r > qw + c) st[mk][r] = -1.0e38f;
        }
      }

      // online softmax over this tile's 128 keys (per lane: q = qw+c)
      float mloc = -3.0e38f;
#pragma unroll
      for (int mk = 0; mk < 8; ++mk)
#pragma unroll
        for (int r = 0; r < 4; ++r) mloc = fmaxf(mloc, st[mk][r]);
      mloc = fmaxf(mloc, __shfl_xor(mloc, 16));
      mloc = fmaxf(mloc, __shfl_xor(mloc, 32));
      const float mnew = fmaxf(mi, mloc);
      const float alpha = exp2f(mi - mnew);
      mi = mnew;
      float sum = 0.0f;
#pragma unroll
      for (int mk = 0; mk < 8; ++mk) {
        short4v pk;
#pragma unroll
        for (int r = 0; r < 4; ++r) {
          const float p = exp2f(st[mk][r] - mnew);
          sum += p;
          pk[r] = (short)f2bf(p);
        }
        *(short4v*)&Ps[wave][c * 128 + (((mk * 2 + (g >> 1)) ^ c7) << 3) + ((g & 1) << 2)] = pk;
      }
      sum += __shfl_xor(sum, 16);
      sum += __shfl_xor(sum, 32);
      li = li * alpha + sum;

      float al[4];
#pragma unroll
      for (int r = 0; r < 4; ++r) al[r] = __shfl(alpha, (lane & 48) | (g * 4 + r));
#pragma unroll
      for (int nd = 0; nd < 4; ++nd)
#pragma unroll
        for (int r = 0; r < 4; ++r) acc[nd][r] *= al[r];

      // O += P * V
#pragma unroll
      for (int kc = 0; kc < 4; ++kc) {
        const int sl = ((kc * 4 + g) ^ c7) << 3;
        const short8 pf = *(const short8*)&Ps[wave][c * 128 + sl];
#pragma unroll
        for (int nd = 0; nd < 4; ++nd) {
          const short8 vf = *(const short8*)&Vs[(nd * 16 + c) * 128 + sl];
          acc[nd] = __builtin_amdgcn_mfma_f32_16x16x32_bf16(pf, vf, acc[nd], 0, 0, 0);
        }
      }
    }

    // epilogue: O / l
    float inv[4];
#pragma unroll
    for (int r = 0; r < 4; ++r) inv[r] = 1.0f / __shfl(li, (lane & 48) | (g * 4 + r));
#pragma unroll
    for (int nd = 0; nd < 4; ++nd)
#pragma unroll
      for (int r = 0; r < 4; ++r)
        obuf[(size_t)(b * Tsz + qw + g * 4 + r) * Dsz + h * 64 + nd * 16 + c] =
            f2bf(acc[nd][r] * inv[r]);
  }
}

extern "C" void kernel_launch(void* const* d_in, const int* in_sizes, int n_in,
                              void* d_out, int out_size, void* d_ws, size_t ws_size,
                              hipStream_t stream) {
  const float* x  = (const float*)d_in[0];
  const float* Wq = (const float*)d_in[1];
  const float* Wk = (const float*)d_in[2];
  const float* Wv = (const float*)d_in[3];
  const float* Wo = (const float*)d_in[4];
  float* out = (float*)d_out;

  // workspace (bf16 elems): wt 4x1M | qkv 3x4M (Q,K natural; slot 2 = VT) | obuf 4M = 40 MiB
  bfu* wt   = (bfu*)d_ws;
  bfu* qkv  = wt  + (size_t)4 * Dsz * Dsz;
  bfu* obuf = qkv + (size_t)3 * Msz * Dsz;

  transpose_w<<<dim3(32, 32, 4), dim3(32, 8), 0, stream>>>(Wq, Wk, Wv, Wo, wt);
  // QKV projections, x converted in-GEMM; Q scale folded into Wq; V -> VT (z==2)
  gemm128<false, true, 128><<<dim3(Dsz / 128, Msz / 128, 3), dim3(256), 0, stream>>>(
      (const void*)x, wt, (void*)qkv, Dsz, Dsz, (size_t)Dsz * Dsz, (size_t)Msz * Dsz);
  attn_kernel<<<dim3(16, Bsz * NHsz), dim3(256), 0, stream>>>(qkv, obuf);
  // output projection -> fp32 d_out (128x64 tiles: 512 blocks = 2/CU)
  gemm128<true, false, 64><<<dim3(Dsz / 64, Msz / 128, 1), dim3(256), 0, stream>>>(
      (const void*)obuf, wt + (size_t)3 * Dsz * Dsz, (void*)out, Dsz, Dsz,
      (size_t)0, (size_t)0);
}